// Round 6
// baseline (130.171 us; speedup 1.0000x reference)
//
#include <hip/hip_runtime.h>

#define NB 4
#define NC 256
#define NI 32
#define NN 4096
#define NSPLIT 8
#define KVQ (NN / NSPLIT)  // 512

typedef short s4v __attribute__((ext_vector_type(4)));
typedef short s8v __attribute__((ext_vector_type(8)));
typedef float f16v __attribute__((ext_vector_type(16)));
typedef unsigned u4v __attribute__((ext_vector_type(4)));

__device__ __forceinline__ unsigned short f2bf(float f) {
  unsigned u = __builtin_bit_cast(unsigned, f);
  return (unsigned short)((u + 0x7FFFu + ((u >> 16) & 1u)) >> 16);
}

__device__ __forceinline__ float fast_exp2(float x) {  // v_exp_f32 computes 2^x
  float r;
  asm("v_exp_f32 %0, %1" : "=v"(r) : "v"(x));
  return r;
}

__device__ __forceinline__ unsigned cvtpk(float lo, float hi) {
  unsigned r;
  asm("v_cvt_pk_bf16_f32 %0, %1, %2" : "=v"(r) : "v"(lo), "v"(hi));
  return r;
}

// ---------------- Kernel 1: fused QKV projection via MFMA (unchanged) ----------------
__global__ __launch_bounds__(256) void qkv_mfma(
    const float* __restrict__ x,
    const float* __restrict__ wq, const float* __restrict__ bq,
    const float* __restrict__ wk, const float* __restrict__ bk,
    const float* __restrict__ wv, const float* __restrict__ bv,
    unsigned short* __restrict__ Qb, unsigned short* __restrict__ Kb,
    unsigned short* __restrict__ V3) {
  __shared__ float part[4][3][32][33];
  const int tid = threadIdx.x;
  const int w = tid >> 6;
  const int lane = tid & 63;
  const int l31 = lane & 31;
  const int hi = lane >> 5;
  const int b = blockIdx.x >> 7;
  const int nb = blockIdx.x & 127;
  const int n0 = nb * 32;

  const float* xb = x + (size_t)b * NC * NN + n0 + l31;

  f16v accQ = {}, accK = {}, accV = {};
#pragma unroll
  for (int j = 0; j < 4; ++j) {
    const int c0 = w * 64 + j * 16;
    float xe[8];
#pragma unroll
    for (int e = 0; e < 8; ++e) xe[e] = xb[(size_t)(c0 + 8 * hi + e) * NN];
    u4v xp;
#pragma unroll
    for (int e2 = 0; e2 < 4; ++e2) xp[e2] = cvtpk(xe[2 * e2], xe[2 * e2 + 1]);
    const s8v xf = __builtin_bit_cast(s8v, xp);

    const int wo_ = l31 * NC + c0 + 8 * hi;
    {
      const float4 a = *reinterpret_cast<const float4*>(&wq[wo_]);
      const float4 c = *reinterpret_cast<const float4*>(&wq[wo_ + 4]);
      u4v wp = {cvtpk(a.x, a.y), cvtpk(a.z, a.w), cvtpk(c.x, c.y), cvtpk(c.z, c.w)};
      accQ = __builtin_amdgcn_mfma_f32_32x32x16_bf16(__builtin_bit_cast(s8v, wp), xf, accQ, 0, 0, 0);
    }
    {
      const float4 a = *reinterpret_cast<const float4*>(&wk[wo_]);
      const float4 c = *reinterpret_cast<const float4*>(&wk[wo_ + 4]);
      u4v wp = {cvtpk(a.x, a.y), cvtpk(a.z, a.w), cvtpk(c.x, c.y), cvtpk(c.z, c.w)};
      accK = __builtin_amdgcn_mfma_f32_32x32x16_bf16(__builtin_bit_cast(s8v, wp), xf, accK, 0, 0, 0);
    }
    {
      const float4 a = *reinterpret_cast<const float4*>(&wv[wo_]);
      const float4 c = *reinterpret_cast<const float4*>(&wv[wo_ + 4]);
      u4v wp = {cvtpk(a.x, a.y), cvtpk(a.z, a.w), cvtpk(c.x, c.y), cvtpk(c.z, c.w)};
      accV = __builtin_amdgcn_mfma_f32_32x32x16_bf16(__builtin_bit_cast(s8v, wp), xf, accV, 0, 0, 0);
    }
  }

#pragma unroll
  for (int r = 0; r < 16; ++r) {
    const int row = (r & 3) + 8 * (r >> 2) + 4 * hi;
    part[w][0][row][l31] = accQ[r];
    part[w][1][row][l31] = accK[r];
    part[w][2][row][l31] = accV[r];
  }
  __syncthreads();

  {
    const int n_l = tid >> 3;
    const int cg = (tid & 7) * 4;
    float sq[4] = {}, sk[4] = {};
#pragma unroll
    for (int ww = 0; ww < 4; ++ww)
#pragma unroll
      for (int jj = 0; jj < 4; ++jj) {
        sq[jj] += part[ww][0][cg + jj][n_l];
        sk[jj] += part[ww][1][cg + jj][n_l];
      }
    s4v qv, kv;
#pragma unroll
    for (int jj = 0; jj < 4; ++jj) {
      qv[jj] = (short)f2bf(sq[jj] + bq[cg + jj]);
      kv[jj] = (short)f2bf((sk[jj] + bk[cg + jj]) * 1.44269504089f);
    }
    *reinterpret_cast<s4v*>(&Qb[((size_t)b * NN + n0 + n_l) * NI + cg]) = qv;
    *reinterpret_cast<s4v*>(&Kb[((size_t)b * NN + n0 + n_l) * NI + cg]) = kv;
  }
  {
    const int n_l = tid & 31;
    const int cb = (tid >> 5) * 4;
    unsigned short* vdst = V3 + (((size_t)b * 128 + nb) * 32) * 32;
#pragma unroll
    for (int i = 0; i < 4; ++i) {
      const int c = cb + i;
      float s = part[0][2][c][n_l] + part[1][2][c][n_l] +
                part[2][2][c][n_l] + part[3][2][c][n_l];
      vdst[(size_t)c * 32 + n_l] = f2bf(s + bv[c]);
    }
  }
}

// ---------------- Kernel 2: flash attention partial, dual-tile ILP ----------------
// grid: NSPLIT * NB * (NN/128) = 1024 blocks, 256 threads = 4 independent waves.
// Per iteration, TWO independent 32-kv tiles (A,B) are processed: 8 frag loads
// issue together, the two S-chains / exp groups / pack groups / PV-chains
// interleave -> ~2x ILP on the former serial critical path. VGPR ~120 (<128
// occupancy cliff, 4 waves/SIMD resident).
__global__ __launch_bounds__(256) void attn_part(
    const unsigned short* __restrict__ Qb, const unsigned short* __restrict__ Kb,
    const unsigned short* __restrict__ V3,
    unsigned short* __restrict__ Opart, float* __restrict__ Lpart) {
  const int tid = threadIdx.x;
  const int split = blockIdx.x >> 7;
  const int bt = blockIdx.x & 127;
  const int b = bt >> 5;
  const int qw = ((bt & 31) << 7) + ((tid >> 6) << 5);  // wave's 32-q base
  const int lane = tid & 63;
  const int l31 = lane & 31;
  const int hi = lane >> 5;

  const unsigned short* qp = Qb + ((size_t)b * NN + qw + l31) * NI + 8 * hi;
  const s8v qf0 = *reinterpret_cast<const s8v*>(qp);
  const s8v qf1 = *reinterpret_cast<const s8v*>(qp + 16);

  const unsigned short* kp = Kb + ((size_t)b * NN + (size_t)split * KVQ + l31) * NI + 8 * hi;
  const unsigned short* vp =
      V3 + (((size_t)b * 128 + (split * KVQ) / 32) * 32 + l31) * 32 + 8 * hi;

  const f16v zero16 = {};
  f16v oacc = {};
  float lsum = 0.f;

  for (int kv = 0; kv < KVQ; kv += 64) {
    // ---- issue all 8 frag loads (two tiles) up front ----
    const s8v kfA0 = *reinterpret_cast<const s8v*>(kp + (size_t)kv * NI);
    const s8v kfA1 = *reinterpret_cast<const s8v*>(kp + (size_t)kv * NI + 16);
    const s8v kfB0 = *reinterpret_cast<const s8v*>(kp + (size_t)(kv + 32) * NI);
    const s8v kfB1 = *reinterpret_cast<const s8v*>(kp + (size_t)(kv + 32) * NI + 16);
    const s8v vfA0 = *reinterpret_cast<const s8v*>(vp + (size_t)kv * 32);
    const s8v vfA1 = *reinterpret_cast<const s8v*>(vp + (size_t)kv * 32 + 16);
    const s8v vfB0 = *reinterpret_cast<const s8v*>(vp + (size_t)(kv + 32) * 32);
    const s8v vfB1 = *reinterpret_cast<const s8v*>(vp + (size_t)(kv + 32) * 32 + 16);

    // ---- two independent S chains ----
    f16v SA = __builtin_amdgcn_mfma_f32_32x32x16_bf16(kfA0, qf0, zero16, 0, 0, 0);
    f16v SB = __builtin_amdgcn_mfma_f32_32x32x16_bf16(kfB0, qf0, zero16, 0, 0, 0);
    SA = __builtin_amdgcn_mfma_f32_32x32x16_bf16(kfA1, qf1, SA, 0, 0, 0);
    SB = __builtin_amdgcn_mfma_f32_32x32x16_bf16(kfB1, qf1, SB, 0, 0, 0);

    float pA[16], pB[16];
#pragma unroll
    for (int r = 0; r < 16; ++r) pA[r] = fast_exp2(SA[r]);
#pragma unroll
    for (int r = 0; r < 16; ++r) pB[r] = fast_exp2(SB[r]);
    {
      float t0 = (pA[0] + pA[1]) + (pA[2] + pA[3]);
      float t1 = (pA[4] + pA[5]) + (pA[6] + pA[7]);
      float t2 = (pA[8] + pA[9]) + (pA[10] + pA[11]);
      float t3 = (pA[12] + pA[13]) + (pA[14] + pA[15]);
      float u0 = (pB[0] + pB[1]) + (pB[2] + pB[3]);
      float u1 = (pB[4] + pB[5]) + (pB[6] + pB[7]);
      float u2 = (pB[8] + pB[9]) + (pB[10] + pB[11]);
      float u3 = (pB[12] + pB[13]) + (pB[14] + pB[15]);
      lsum += ((t0 + t1) + (t2 + t3)) + ((u0 + u1) + (u2 + u3));
    }

    unsigned dA[8], dB[8];
#pragma unroll
    for (int j = 0; j < 8; ++j) dA[j] = cvtpk(pA[2 * j], pA[2 * j + 1]);
#pragma unroll
    for (int j = 0; j < 8; ++j) dB[j] = cvtpk(pB[2 * j], pB[2 * j + 1]);
    asm("v_permlane32_swap_b32 %0, %1" : "+v"(dA[0]), "+v"(dA[2]));
    asm("v_permlane32_swap_b32 %0, %1" : "+v"(dA[1]), "+v"(dA[3]));
    asm("v_permlane32_swap_b32 %0, %1" : "+v"(dA[4]), "+v"(dA[6]));
    asm("v_permlane32_swap_b32 %0, %1" : "+v"(dA[5]), "+v"(dA[7]));
    asm("v_permlane32_swap_b32 %0, %1" : "+v"(dB[0]), "+v"(dB[2]));
    asm("v_permlane32_swap_b32 %0, %1" : "+v"(dB[1]), "+v"(dB[3]));
    asm("v_permlane32_swap_b32 %0, %1" : "+v"(dB[4]), "+v"(dB[6]));
    asm("v_permlane32_swap_b32 %0, %1" : "+v"(dB[5]), "+v"(dB[7]));

    const u4v aA0 = {dA[0], dA[1], dA[2], dA[3]};
    const u4v aA1 = {dA[4], dA[5], dA[6], dA[7]};
    const u4v aB0 = {dB[0], dB[1], dB[2], dB[3]};
    const u4v aB1 = {dB[4], dB[5], dB[6], dB[7]};
    oacc = __builtin_amdgcn_mfma_f32_32x32x16_bf16(__builtin_bit_cast(s8v, aA0), vfA0, oacc, 0, 0, 0);
    oacc = __builtin_amdgcn_mfma_f32_32x32x16_bf16(__builtin_bit_cast(s8v, aA1), vfA1, oacc, 0, 0, 0);
    oacc = __builtin_amdgcn_mfma_f32_32x32x16_bf16(__builtin_bit_cast(s8v, aB0), vfB0, oacc, 0, 0, 0);
    oacc = __builtin_amdgcn_mfma_f32_32x32x16_bf16(__builtin_bit_cast(s8v, aB1), vfB1, oacc, 0, 0, 0);
  }

  lsum += __shfl_xor(lsum, 32, 64);

  unsigned short* op = Opart + (((size_t)split * NB + b) * NN + qw) * NI + l31;
#pragma unroll
  for (int r = 0; r < 16; ++r) {
    const int qr = (r & 3) + 8 * (r >> 2) + 4 * hi;
    op[(size_t)qr * NI] = f2bf(oacc[r]);
  }
  if (hi == 0)
    Lpart[((size_t)split * NB + b) * NN + qw + l31] = lsum;
}

// ---------------- Kernel 3: combine partials + output projection (unchanged) ----------------
__global__ __launch_bounds__(256) void combine_proj(
    const unsigned short* __restrict__ Opart, const float* __restrict__ Lpart,
    const float* __restrict__ wo, const float* __restrict__ bo,
    float* __restrict__ out) {
  __shared__ __align__(16) float o_lds[NI][65];
  __shared__ float linv[64];
  const int tid = threadIdx.x;
  const int g2 = blockIdx.x >> 8;
  const int bt = blockIdx.x & 255;
  const int b = bt >> 6;
  const int q0 = (bt & 63) * 64;

  {
    const int qs = tid >> 2, cg = tid & 3;
    float s[8] = {};
#pragma unroll
    for (int sp = 0; sp < NSPLIT; ++sp) {
      const s8v v = *reinterpret_cast<const s8v*>(
          &Opart[(((size_t)sp * NB + b) * NN + q0 + qs) * NI + cg * 8]);
#pragma unroll
      for (int e = 0; e < 8; ++e) {
        const unsigned u = (unsigned)(unsigned short)v[e];
        s[e] += __builtin_bit_cast(float, u << 16);
      }
    }
#pragma unroll
    for (int e = 0; e < 8; ++e) o_lds[cg * 8 + e][qs] = s[e];
  }
  if (tid < 64) {
    float l = 0.f;
#pragma unroll
    for (int sp = 0; sp < NSPLIT; ++sp)
      l += Lpart[((size_t)sp * NB + b) * NN + q0 + tid];
    linv[tid] = 1.0f / l;
  }
  __syncthreads();

  const int q = tid & 63;
  const float il = linv[q];
  float xv[NI];
#pragma unroll
  for (int c = 0; c < NI; ++c) xv[c] = o_lds[c][q] * il;

  float* op2 = out + ((size_t)b * NC) * NN + q0 + q;
  const int co0 = g2 * 32 + (tid >> 6) * 8;
#pragma unroll
  for (int cc = 0; cc < 8; ++cc) {
    const int co = co0 + cc;
    float a = bo[co];
#pragma unroll
    for (int c4 = 0; c4 < 8; ++c4) {
      const float4 w4 = *reinterpret_cast<const float4*>(&wo[co * NI + c4 * 4]);
      a += w4.x * xv[c4 * 4] + w4.y * xv[c4 * 4 + 1] +
           w4.z * xv[c4 * 4 + 2] + w4.w * xv[c4 * 4 + 3];
    }
    op2[(size_t)co * NN] = a;
  }
}

extern "C" void kernel_launch(void* const* d_in, const int* in_sizes, int n_in,
                              void* d_out, int out_size, void* d_ws, size_t ws_size,
                              hipStream_t stream) {
  const float* x  = (const float*)d_in[0];
  const float* wq = (const float*)d_in[1];
  const float* bq = (const float*)d_in[2];
  const float* wk = (const float*)d_in[3];
  const float* bk = (const float*)d_in[4];
  const float* wv = (const float*)d_in[5];
  const float* bv = (const float*)d_in[6];
  const float* wo = (const float*)d_in[7];
  const float* bo = (const float*)d_in[8];
  float* out = (float*)d_out;

  unsigned short* Qb = (unsigned short*)d_ws;                 // [NB][NN][NI] bf16 (1 MB)
  unsigned short* Kb = Qb + (size_t)NB * NN * NI;             // 1 MB (pre-scaled by log2e)
  unsigned short* V3 = Kb + (size_t)NB * NN * NI;             // [NB][128][32][32] 1 MB
  unsigned short* Opart = V3 + (size_t)NB * NN * NI;          // [8][NB][NN][NI] bf16 (8 MB)
  float* Lpart = (float*)(Opart + (size_t)NSPLIT * NB * NN * NI);  // [8][NB][NN] (512 KB)

  qkv_mfma<<<NB * (NN / 32), 256, 0, stream>>>(x, wq, bq, wk, bk, wv, bv, Qb, Kb, V3);
  attn_part<<<NSPLIT * NB * (NN / 128), 256, 0, stream>>>(Qb, Kb, V3, Opart, Lpart);
  combine_proj<<<8 * NB * (NN / 64), 256, 0, stream>>>(Opart, Lpart, wo, bo, out);
}

// Round 9
// 128.145 us; speedup vs baseline: 1.0158x; 1.0158x over previous
//
#include <hip/hip_runtime.h>

#define NB 4
#define NC 256
#define NI 32
#define NN 4096
#define NSPLIT 8
#define KVQ (NN / NSPLIT)  // 512

typedef short s4v __attribute__((ext_vector_type(4)));
typedef short s8v __attribute__((ext_vector_type(8)));
typedef float f16v __attribute__((ext_vector_type(16)));
typedef unsigned u4v __attribute__((ext_vector_type(4)));

__device__ __forceinline__ unsigned short f2bf(float f) {
  unsigned u = __builtin_bit_cast(unsigned, f);
  return (unsigned short)((u + 0x7FFFu + ((u >> 16) & 1u)) >> 16);
}

__device__ __forceinline__ float fast_exp2(float x) {  // v_exp_f32 computes 2^x
  float r;
  asm("v_exp_f32 %0, %1" : "=v"(r) : "v"(x));
  return r;
}

__device__ __forceinline__ unsigned cvtpk(float lo, float hi) {
  unsigned r;
  asm("v_cvt_pk_bf16_f32 %0, %1, %2" : "=v"(r) : "v"(lo), "v"(hi));
  return r;
}

// ---------------- Kernel 0: one-shot W fragment pre-transpose ----------------
// grid: 3 proj * 16 cslices = 48 blocks, 256 threads.
// Wf[p][cs][lane][e2] (u32 = 2 bf16): lane l gets W_p[l&31][cs*16 + 8*(l>>5) + 2e2+{0,1}]
// == exactly the MFMA A-frag element order, so qkv loads become coalesced 16B/lane.
__global__ __launch_bounds__(256) void w_prep(
    const float* __restrict__ wq, const float* __restrict__ wk,
    const float* __restrict__ wv, unsigned* __restrict__ Wf) {
  const int p = blockIdx.x >> 4;
  const int cs = blockIdx.x & 15;
  const float* w = p == 0 ? wq : (p == 1 ? wk : wv);
  const int t = threadIdx.x;
  const int l = t >> 2, e2 = t & 3;
  const int row = l & 31, hi = l >> 5;
  const float2 v =
      *reinterpret_cast<const float2*>(&w[row * NC + cs * 16 + 8 * hi + 2 * e2]);
  Wf[((p * 16 + cs) * 64 + l) * 4 + e2] =
      ((unsigned)f2bf(v.y) << 16) | (unsigned)f2bf(v.x);
}

// ---------------- Kernel 1: fused QKV projection via MFMA ----------------
// grid: NB * (NN/32) = 512 blocks, 256 threads = 4 waves.
// W A-frags now read from fragment-ordered Wf (coalesced, replaces 64-segment
// gathers + per-block fp32->bf16 convert). Everything else identical to R5.
__global__ __launch_bounds__(256) void qkv_mfma(
    const float* __restrict__ x, const unsigned* __restrict__ Wf,
    const float* __restrict__ bq, const float* __restrict__ bk,
    const float* __restrict__ bv,
    unsigned short* __restrict__ Qb, unsigned short* __restrict__ Kb,
    unsigned short* __restrict__ V3) {
  __shared__ float part[4][3][32][33];
  const int tid = threadIdx.x;
  const int w = tid >> 6;
  const int lane = tid & 63;
  const int l31 = lane & 31;
  const int hi = lane >> 5;
  const int b = blockIdx.x >> 7;
  const int nb = blockIdx.x & 127;
  const int n0 = nb * 32;

  const float* xb = x + (size_t)b * NC * NN + n0 + l31;

  f16v accQ = {}, accK = {}, accV = {};
#pragma unroll
  for (int j = 0; j < 4; ++j) {
    const int c0 = w * 64 + j * 16;
    const int cs = w * 4 + j;
    float xe[8];
#pragma unroll
    for (int e = 0; e < 8; ++e) xe[e] = xb[(size_t)(c0 + 8 * hi + e) * NN];
    u4v xp;
#pragma unroll
    for (int e2 = 0; e2 < 4; ++e2) xp[e2] = cvtpk(xe[2 * e2], xe[2 * e2 + 1]);
    const s8v xf = __builtin_bit_cast(s8v, xp);

    const s8v wfq = *reinterpret_cast<const s8v*>(&Wf[((0 * 16 + cs) * 64 + lane) * 4]);
    const s8v wfk = *reinterpret_cast<const s8v*>(&Wf[((1 * 16 + cs) * 64 + lane) * 4]);
    const s8v wfv = *reinterpret_cast<const s8v*>(&Wf[((2 * 16 + cs) * 64 + lane) * 4]);
    accQ = __builtin_amdgcn_mfma_f32_32x32x16_bf16(wfq, xf, accQ, 0, 0, 0);
    accK = __builtin_amdgcn_mfma_f32_32x32x16_bf16(wfk, xf, accK, 0, 0, 0);
    accV = __builtin_amdgcn_mfma_f32_32x32x16_bf16(wfv, xf, accV, 0, 0, 0);
  }

#pragma unroll
  for (int r = 0; r < 16; ++r) {
    const int row = (r & 3) + 8 * (r >> 2) + 4 * hi;
    part[w][0][row][l31] = accQ[r];
    part[w][1][row][l31] = accK[r];
    part[w][2][row][l31] = accV[r];
  }
  __syncthreads();

  {
    const int n_l = tid >> 3;
    const int cg = (tid & 7) * 4;
    float sq[4] = {}, sk[4] = {};
#pragma unroll
    for (int ww = 0; ww < 4; ++ww)
#pragma unroll
      for (int jj = 0; jj < 4; ++jj) {
        sq[jj] += part[ww][0][cg + jj][n_l];
        sk[jj] += part[ww][1][cg + jj][n_l];
      }
    s4v qv, kv;
#pragma unroll
    for (int jj = 0; jj < 4; ++jj) {
      qv[jj] = (short)f2bf(sq[jj] + bq[cg + jj]);
      kv[jj] = (short)f2bf((sk[jj] + bk[cg + jj]) * 1.44269504089f);
    }
    *reinterpret_cast<s4v*>(&Qb[((size_t)b * NN + n0 + n_l) * NI + cg]) = qv;
    *reinterpret_cast<s4v*>(&Kb[((size_t)b * NN + n0 + n_l) * NI + cg]) = kv;
  }
  {
    const int n_l = tid & 31;
    const int cb = (tid >> 5) * 4;
    unsigned short* vdst = V3 + (((size_t)b * 128 + nb) * 32) * 32;
#pragma unroll
    for (int i = 0; i < 4; ++i) {
      const int c = cb + i;
      float s = part[0][2][c][n_l] + part[1][2][c][n_l] +
                part[2][2][c][n_l] + part[3][2][c][n_l];
      vdst[(size_t)c * 32 + n_l] = f2bf(s + bv[c]);
    }
  }
}

// ---------------- Kernel 2: flash attention partial (R5-verified, unchanged) ----------------
__global__ __launch_bounds__(256) void attn_part(
    const unsigned short* __restrict__ Qb, const unsigned short* __restrict__ Kb,
    const unsigned short* __restrict__ V3,
    unsigned short* __restrict__ Opart, float* __restrict__ Lpart) {
  const int tid = threadIdx.x;
  const int split = blockIdx.x >> 7;
  const int bt = blockIdx.x & 127;
  const int b = bt >> 5;
  const int qw = ((bt & 31) << 7) + ((tid >> 6) << 5);  // wave's 32-q base
  const int lane = tid & 63;
  const int l31 = lane & 31;
  const int hi = lane >> 5;

  const unsigned short* qp = Qb + ((size_t)b * NN + qw + l31) * NI + 8 * hi;
  const s8v qf0 = *reinterpret_cast<const s8v*>(qp);
  const s8v qf1 = *reinterpret_cast<const s8v*>(qp + 16);

  const unsigned short* kp = Kb + ((size_t)b * NN + (size_t)split * KVQ + l31) * NI + 8 * hi;
  const unsigned short* vp =
      V3 + (((size_t)b * 128 + (split * KVQ) / 32) * 32 + l31) * 32 + 8 * hi;

  const f16v zero16 = {};
  f16v oacc = {};
  float lsum = 0.f;

#pragma unroll 4
  for (int kv = 0; kv < KVQ; kv += 32) {
    const s8v kf0 = *reinterpret_cast<const s8v*>(kp + (size_t)kv * NI);
    const s8v kf1 = *reinterpret_cast<const s8v*>(kp + (size_t)kv * NI + 16);
    const s8v vf0 = *reinterpret_cast<const s8v*>(vp + (size_t)kv * 32);
    const s8v vf1 = *reinterpret_cast<const s8v*>(vp + (size_t)kv * 32 + 16);

    f16v S = __builtin_amdgcn_mfma_f32_32x32x16_bf16(kf0, qf0, zero16, 0, 0, 0);
    S = __builtin_amdgcn_mfma_f32_32x32x16_bf16(kf1, qf1, S, 0, 0, 0);

    float p[16];
#pragma unroll
    for (int r = 0; r < 16; ++r) p[r] = fast_exp2(S[r]);
    float t0 = (p[0] + p[1]) + (p[2] + p[3]);
    float t1 = (p[4] + p[5]) + (p[6] + p[7]);
    float t2 = (p[8] + p[9]) + (p[10] + p[11]);
    float t3 = (p[12] + p[13]) + (p[14] + p[15]);
    lsum += (t0 + t1) + (t2 + t3);

    unsigned d[8];
#pragma unroll
    for (int j = 0; j < 8; ++j) d[j] = cvtpk(p[2 * j], p[2 * j + 1]);
    asm("v_permlane32_swap_b32 %0, %1" : "+v"(d[0]), "+v"(d[2]));
    asm("v_permlane32_swap_b32 %0, %1" : "+v"(d[1]), "+v"(d[3]));
    asm("v_permlane32_swap_b32 %0, %1" : "+v"(d[4]), "+v"(d[6]));
    asm("v_permlane32_swap_b32 %0, %1" : "+v"(d[5]), "+v"(d[7]));

    const u4v a0 = {d[0], d[1], d[2], d[3]};
    const u4v a1 = {d[4], d[5], d[6], d[7]};
    oacc = __builtin_amdgcn_mfma_f32_32x32x16_bf16(__builtin_bit_cast(s8v, a0), vf0, oacc, 0, 0, 0);
    oacc = __builtin_amdgcn_mfma_f32_32x32x16_bf16(__builtin_bit_cast(s8v, a1), vf1, oacc, 0, 0, 0);
  }

  lsum += __shfl_xor(lsum, 32, 64);

  unsigned short* op = Opart + (((size_t)split * NB + b) * NN + qw) * NI + l31;
#pragma unroll
  for (int r = 0; r < 16; ++r) {
    const int qr = (r & 3) + 8 * (r >> 2) + 4 * hi;
    op[(size_t)qr * NI] = f2bf(oacc[r]);
  }
  if (hi == 0)
    Lpart[((size_t)split * NB + b) * NN + qw + l31] = lsum;
}

// ---------------- Kernel 3: combine partials + output projection (R5-verified, unchanged) ----------------
__global__ __launch_bounds__(256) void combine_proj(
    const unsigned short* __restrict__ Opart, const float* __restrict__ Lpart,
    const float* __restrict__ wo, const float* __restrict__ bo,
    float* __restrict__ out) {
  __shared__ __align__(16) float o_lds[NI][65];
  __shared__ float linv[64];
  const int tid = threadIdx.x;
  const int g2 = blockIdx.x >> 8;        // co-group 0..7 (32 channels each)
  const int bt = blockIdx.x & 255;
  const int b = bt >> 6;
  const int q0 = (bt & 63) * 64;

  {
    const int qs = tid >> 2, cg = tid & 3;
    float s[8] = {};
#pragma unroll
    for (int sp = 0; sp < NSPLIT; ++sp) {
      const s8v v = *reinterpret_cast<const s8v*>(
          &Opart[(((size_t)sp * NB + b) * NN + q0 + qs) * NI + cg * 8]);
#pragma unroll
      for (int e = 0; e < 8; ++e) {
        const unsigned u = (unsigned)(unsigned short)v[e];
        s[e] += __builtin_bit_cast(float, u << 16);
      }
    }
#pragma unroll
    for (int e = 0; e < 8; ++e) o_lds[cg * 8 + e][qs] = s[e];
  }
  if (tid < 64) {
    float l = 0.f;
#pragma unroll
    for (int sp = 0; sp < NSPLIT; ++sp)
      l += Lpart[((size_t)sp * NB + b) * NN + q0 + tid];
    linv[tid] = 1.0f / l;
  }
  __syncthreads();

  const int q = tid & 63;
  const float il = linv[q];
  float xv[NI];
#pragma unroll
  for (int c = 0; c < NI; ++c) xv[c] = o_lds[c][q] * il;

  float* op2 = out + ((size_t)b * NC) * NN + q0 + q;
  const int co0 = g2 * 32 + (tid >> 6) * 8;
#pragma unroll
  for (int cc = 0; cc < 8; ++cc) {
    const int co = co0 + cc;
    float a = bo[co];
#pragma unroll
    for (int c4 = 0; c4 < 8; ++c4) {
      const float4 w4 = *reinterpret_cast<const float4*>(&wo[co * NI + c4 * 4]);
      a += w4.x * xv[c4 * 4] + w4.y * xv[c4 * 4 + 1] +
           w4.z * xv[c4 * 4 + 2] + w4.w * xv[c4 * 4 + 3];
    }
    op2[(size_t)co * NN] = a;
  }
}

extern "C" void kernel_launch(void* const* d_in, const int* in_sizes, int n_in,
                              void* d_out, int out_size, void* d_ws, size_t ws_size,
                              hipStream_t stream) {
  const float* x  = (const float*)d_in[0];
  const float* wq = (const float*)d_in[1];
  const float* bq = (const float*)d_in[2];
  const float* wk = (const float*)d_in[3];
  const float* bk = (const float*)d_in[4];
  const float* wv = (const float*)d_in[5];
  const float* bv = (const float*)d_in[6];
  const float* wo = (const float*)d_in[7];
  const float* bo = (const float*)d_in[8];
  float* out = (float*)d_out;

  unsigned short* Qb = (unsigned short*)d_ws;                 // [NB][NN][NI] bf16 (1 MB)
  unsigned short* Kb = Qb + (size_t)NB * NN * NI;             // 1 MB (pre-scaled by log2e)
  unsigned short* V3 = Kb + (size_t)NB * NN * NI;             // [NB][128][32][32] 1 MB
  unsigned short* Opart = V3 + (size_t)NB * NN * NI;          // [8][NB][NN][NI] bf16 (8 MB)
  float* Lpart = (float*)(Opart + (size_t)NSPLIT * NB * NN * NI);  // [8][NB][NN] (512 KB)
  unsigned* Wf = (unsigned*)(Lpart + (size_t)NSPLIT * NB * NN);    // [3][16][64][4] u32 (48 KB)

  w_prep<<<48, 256, 0, stream>>>(wq, wk, wv, Wf);
  qkv_mfma<<<NB * (NN / 32), 256, 0, stream>>>(x, Wf, bq, bk, bv, Qb, Kb, V3);
  attn_part<<<NSPLIT * NB * (NN / 128), 256, 0, stream>>>(Qb, Kb, V3, Opart, Lpart);
  combine_proj<<<8 * NB * (NN / 64), 256, 0, stream>>>(Opart, Lpart, wo, bo, out);
}